// Round 6
// baseline (283.632 us; speedup 1.0000x reference)
//
#include <hip/hip_runtime.h>
#include <hip/hip_bf16.h>

typedef __attribute__((ext_vector_type(8))) short short8;
typedef __attribute__((ext_vector_type(4))) float floatx4;
typedef __attribute__((ext_vector_type(4))) unsigned uint4v;

#define FDIM 512
#define CDIM 64
#define ODIM 256
#define TR   32      // rows per tile
#define XSF  516     // xs row stride in floats (512 + 4 -> +16B pad per row)
#define STS 40       // sT row stride (ushort)
#define MAXP 512

// round-to-nearest-even fp32 -> bf16
__device__ __forceinline__ ushort f2bf(float f) {
    union { float f; unsigned u; } v; v.f = f;
    unsigned r = v.u + 0x7FFFu + ((v.u >> 16) & 1u);
    return (ushort)(r >> 16);
}
__device__ __forceinline__ float bf2f(unsigned hi16) {
    union { unsigned u; float f; } v; v.u = hi16 << 16; return v.f;
}

// async 16B/lane global -> LDS (lds dest = wave-uniform base + lane*16)
__device__ __forceinline__ void gld16(const float* g, float* lds_base) {
    __builtin_amdgcn_global_load_lds(
        (const __attribute__((address_space(1))) unsigned int*)(const void*)g,
        (__attribute__((address_space(3))) unsigned int*)(void*)lds_base,
        16, 0, 0);
}

// ---------------- WpT[c][f] = bf16(Wp[f][c]) (64 KB, L2/L3-resident) -------
__global__ __launch_bounds__(256) void kWpT(const float* __restrict__ Wp,
                                            ushort* __restrict__ WpT) {
    int g = blockIdx.x * 256 + threadIdx.x;   // 0..32767
    int f = g >> 6, c = g & 63;
    WpT[c * FDIM + f] = f2bf(Wp[f * CDIM + c]);
}

// ---------------- Fused: per 32-row tile, s=softmax(xWp+bp); M_p += s^T x --
// Grid = P blocks; block b handles tiles b, b+P, ... 512 threads = 8 waves.
// x staged fp32 via async global_load_lds; bf16 cvt at frag-build time.
// Per-block output: bf16 partial M [64c][512f] + fp32 colsum partial [64c].
__global__ __launch_bounds__(512, 4) void kFused(
        const float* __restrict__ x, const ushort* __restrict__ WpT,
        const float* __restrict__ bp, ushort* __restrict__ part,
        float* __restrict__ cpart, int N, int nTiles, int P) {
    __shared__ float  xsf[TR * XSF];     // 64.5 KB fp32 x tile (padded rows)
    __shared__ ushort sT[CDIM][STS];     //  5.0 KB s^T [c][row]
    __shared__ float  red1[TR][4];
    __shared__ float  red2[TR][4];
    __shared__ float  cred[CDIM][2];

    const int t    = threadIdx.x;
    const int w    = t >> 6;        // 0..7
    const int lane = t & 63;
    const int l16  = lane & 15;
    const int q    = lane >> 4;
    const int ci   = w & 3;         // phase-1 c-tile (16 c)
    const int rg   = w >> 2;        // phase-1 row half (rows 16rg..16rg+15)

    // persistent M slice: c 0..63 (mt), f in [64w,64w+64) (nt) -> 64 VGPRs
    floatx4 acc[4][4];
#pragma unroll
    for (int mt = 0; mt < 4; ++mt)
#pragma unroll
        for (int nt = 0; nt < 4; ++nt) acc[mt][nt] = (floatx4){0.f, 0.f, 0.f, 0.f};
    float csp[4] = {0.f, 0.f, 0.f, 0.f};

    float bpv[4];
#pragma unroll
    for (int reg = 0; reg < 4; ++reg) bpv[reg] = bp[16 * ci + 4 * q + reg];

    const ushort* wb = WpT + (size_t)(16 * ci + l16) * FDIM + q * 8;

    for (int tile = blockIdx.x; tile < nTiles; tile += P) {
        __syncthreads();             // guard xsf vs previous iteration readers
        const int row0 = tile * TR;

        // ---- stage x tile: 32 rows x 2 KB, async, 8 chunks/wave ----
#pragma unroll
        for (int i = 0; i < 8; ++i) {
            const int c0 = w * 8 + i;          // 0..63
            const int r  = c0 >> 1;
            const int h  = c0 & 1;
            float* lb = xsf + r * XSF + h * 256;           // wave-uniform
            if (row0 + r < N) {
                const float* g = x + (size_t)(row0 + r) * FDIM + h * 256 + lane * 4;
                gld16(g, lb);
            } else {
                *(floatx4*)(lb + lane * 4) = (floatx4){0.f, 0.f, 0.f, 0.f};
            }
        }
        __syncthreads();             // drains async queue (vmcnt before barrier)

        // ---- phase 1: logitsT[c=16ci..+16][rows 16rg..+16], K=512 ----
        floatx4 acc1 = (floatx4){0.f, 0.f, 0.f, 0.f};
        const float* xr = xsf + (16 * rg + l16) * XSF;   // B row = this lane's row
#pragma unroll
        for (int kb = 0; kb < 4; ++kb) {
            short8 af[4];
#pragma unroll
            for (int ki = 0; ki < 4; ++ki)
                af[ki] = *(const short8*)(wb + kb * 128 + ki * 32);
#pragma unroll
            for (int ki = 0; ki < 4; ++ki) {
                const int off = kb * 128 + ki * 32 + q * 8;
                floatx4 u0 = *(const floatx4*)(xr + off);
                floatx4 u1 = *(const floatx4*)(xr + off + 4);
                short8 b;
                b[0] = (short)f2bf(u0[0]); b[1] = (short)f2bf(u0[1]);
                b[2] = (short)f2bf(u0[2]); b[3] = (short)f2bf(u0[3]);
                b[4] = (short)f2bf(u1[0]); b[5] = (short)f2bf(u1[1]);
                b[6] = (short)f2bf(u1[2]); b[7] = (short)f2bf(u1[3]);
                acc1 = __builtin_amdgcn_mfma_f32_16x16x32_bf16(af[ki], b, acc1, 0, 0, 0);
            }
        }

        // ---- softmax over c per row; lane: c=16ci+4q+reg, row=16rg+l16 ----
        const int row = 16 * rg + l16;
        float lg[4];
#pragma unroll
        for (int reg = 0; reg < 4; ++reg) lg[reg] = acc1[reg] + bpv[reg];
        float m = fmaxf(fmaxf(lg[0], lg[1]), fmaxf(lg[2], lg[3]));
        m = fmaxf(m, __shfl_xor(m, 16));
        m = fmaxf(m, __shfl_xor(m, 32));
        if (lane < 16) red1[16 * rg + lane][ci] = m;
        __syncthreads();
        const float rmax = fmaxf(fmaxf(red1[row][0], red1[row][1]),
                                 fmaxf(red1[row][2], red1[row][3]));
        float p = 0.f;
#pragma unroll
        for (int reg = 0; reg < 4; ++reg) {
            float e = __expf(lg[reg] - rmax);
            lg[reg] = e; p += e;
        }
        p += __shfl_xor(p, 16);
        p += __shfl_xor(p, 32);
        if (lane < 16) red2[16 * rg + lane][ci] = p;
        __syncthreads();
        const float rsi = 1.0f / (red2[row][0] + red2[row][1] +
                                  red2[row][2] + red2[row][3]);
        const bool valid = (row0 + row) < N;
#pragma unroll
        for (int reg = 0; reg < 4; ++reg) {
            float s = valid ? lg[reg] * rsi : 0.f;
            sT[16 * ci + 4 * q + reg][row] = f2bf(s);
            csp[reg] += s;
        }
        __syncthreads();   // sT ready; xsf still intact

        // ---- phase 2: acc += s^T x over this tile (K=32 rows) ----
        short8 as_[4];
#pragma unroll
        for (int mt = 0; mt < 4; ++mt)
            as_[mt] = *(const short8*)&sT[16 * mt + l16][q * 8];
#pragma unroll
        for (int nt = 0; nt < 4; ++nt) {
            const int f = 64 * w + 16 * nt + l16;
            short8 b;
#pragma unroll
            for (int j = 0; j < 8; ++j)
                b[j] = (short)f2bf(xsf[(q * 8 + j) * XSF + f]);
#pragma unroll
            for (int mt = 0; mt < 4; ++mt)
                acc[mt][nt] = __builtin_amdgcn_mfma_f32_16x16x32_bf16(
                    as_[mt], b, acc[mt][nt], 0, 0, 0);
        }
    }

    // ---- per-block colsum partial (fp32, no atomics) ----
#pragma unroll
    for (int reg = 0; reg < 4; ++reg) {
        float v = csp[reg];
        v += __shfl_xor(v, 1); v += __shfl_xor(v, 2);
        v += __shfl_xor(v, 4); v += __shfl_xor(v, 8);
        if (l16 == 0) cred[16 * ci + 4 * q + reg][rg] = v;
    }
    __syncthreads();   // all waves done with xsf (phase-2 complete)
    if (t < 64) cpart[(size_t)blockIdx.x * CDIM + t] = cred[t][0] + cred[t][1];

    // ---- flush: acc -> xsf scratch (bf16) -> coalesced uint4 store ----
    ushort* xf = (ushort*)xsf;
#pragma unroll
    for (int mt = 0; mt < 4; ++mt)
#pragma unroll
        for (int nt = 0; nt < 4; ++nt)
#pragma unroll
            for (int reg = 0; reg < 4; ++reg)
                xf[(16 * mt + 4 * q + reg) * FDIM + 64 * w + 16 * nt + l16] =
                    f2bf(acc[mt][nt][reg]);
    __syncthreads();
    const uint4v* src = (const uint4v*)xf;
    uint4v* dst = (uint4v*)(part + (size_t)blockIdx.x * (CDIM * FDIM));
#pragma unroll
    for (int i = 0; i < 8; ++i)
        dst[i * 512 + t] = src[i * 512 + t];
}

// ---------------- stage-1 reduce: P partials -> 8 fp32 slices + colsum -----
// grid (64 c, 8 p-chunks), 512 threads (t = f).
__global__ __launch_bounds__(512) void kR(const ushort* __restrict__ part,
                                          const float* __restrict__ cpart,
                                          float* __restrict__ colsum,
                                          float* __restrict__ Mp,
                                          int P, int pch) {
    __shared__ float ws8[8];
    const int c = blockIdx.x, pc = blockIdx.y, t = threadIdx.x;
    const int p0 = pc * pch, p1 = min(p0 + pch, P);

    float sum = 0.f;
    const ushort* pp = part + (size_t)c * FDIM + t;
#pragma unroll 4
    for (int p = p0; p < p1; ++p)
        sum += bf2f((unsigned)pp[(size_t)p * (CDIM * FDIM)]);
    Mp[((size_t)pc * CDIM + c) * FDIM + t] = sum;

    // colsum chunk (p = p0 + t)
    float cv = 0.f;
    {
        int p = p0 + t;
        if (p < p1) cv = cpart[(size_t)p * CDIM + c];
    }
    cv += __shfl_xor(cv, 1);  cv += __shfl_xor(cv, 2);
    cv += __shfl_xor(cv, 4);  cv += __shfl_xor(cv, 8);
    cv += __shfl_xor(cv, 16); cv += __shfl_xor(cv, 32);
    if ((t & 63) == 0) ws8[t >> 6] = cv;
    __syncthreads();
    if (t == 0) {
        float tot = 0.f;
#pragma unroll
        for (int i = 0; i < 8; ++i) tot += ws8[i];
        atomicAdd(colsum + c, tot);     // 512 adds total, uncontended
    }
}

// ---------------- epilogue: Mp -> M -> pooled -> out -----------------------
__global__ __launch_bounds__(512) void kC(const float* __restrict__ Mp,
                                          const float* __restrict__ colsum,
                                          const float* __restrict__ We,
                                          const float* __restrict__ be,
                                          const float* __restrict__ Wo,
                                          const float* __restrict__ bo,
                                          float* __restrict__ out) {
    __shared__ float Mrow[512];
    __shared__ float pooled[512];
    __shared__ float halves[2][256];
    const int c = blockIdx.x, t = threadIdx.x;

    float sum = 0.f;
#pragma unroll
    for (int pc = 0; pc < 8; ++pc)
        sum += Mp[((size_t)pc * CDIM + c) * FDIM + t];
    Mrow[t] = sum;
    __syncthreads();

    float a = colsum[c] * be[t];
#pragma unroll 16
    for (int k = 0; k < FDIM; ++k)
        a = fmaf(Mrow[k], We[(size_t)k * FDIM + t], a);
    pooled[t] = a;
    __syncthreads();

    const int o = t & 255, h = t >> 8;
    float b = 0.f;
#pragma unroll 16
    for (int kk = 0; kk < 256; ++kk) {
        int k = h * 256 + kk;
        b = fmaf(pooled[k], Wo[(size_t)k * ODIM + o], b);
    }
    halves[h][o] = b;
    __syncthreads();
    if (t < 256)
        out[(size_t)c * ODIM + t] = halves[0][t] + halves[1][t] + bo[t];
}

// ---------------------------------------------------------------------------
extern "C" void kernel_launch(void* const* d_in, const int* in_sizes, int n_in,
                              void* d_out, int out_size, void* d_ws, size_t ws_size,
                              hipStream_t stream) {
    const float* x  = (const float*)d_in[0];
    // d_in[1] edge_index, d_in[2] batch: unused by reference output
    const float* Wp = (const float*)d_in[3];
    const float* bp = (const float*)d_in[4];
    const float* We = (const float*)d_in[5];
    const float* be = (const float*)d_in[6];
    const float* Wo = (const float*)d_in[7];
    const float* bo = (const float*)d_in[8];
    float* out = (float*)d_out;

    const int N = in_sizes[0] / FDIM;          // 50000
    const int nTiles = (N + TR - 1) / TR;      // 1563

    // ws bytes:
    //   [0,       65536)  WpT bf16
    //   [65536,   65792)  colsum fp32
    //   [66560,  266752)  cpart fp32 (<=782 x 64)
    //   [266752,1315328)  Mp fp32 (8 x 64 x 512)
    //   [1315328, ...)    part bf16 (P x 64 KB)
    char*   wsb    = (char*)d_ws;
    ushort* WpT    = (ushort*)wsb;
    float*  colsum = (float*)(wsb + 65536);
    float*  cpart  = (float*)(wsb + 66560);
    float*  Mp     = (float*)(wsb + 266752);
    const size_t PART_OFF = 1315328;
    ushort* part   = (ushort*)(wsb + PART_OFF);

    size_t avail = (ws_size > PART_OFF + 65536) ? (ws_size - PART_OFF) / 65536 : 1;
    int P = (int)(avail < (size_t)MAXP ? avail : (size_t)MAXP);
    if (P > nTiles) P = nTiles;
    if (P < 1) P = 1;
    const int pch = (P + 7) / 8;

    hipMemsetAsync(colsum, 0, 256, stream);
    kWpT<<<128, 256, 0, stream>>>(Wp, WpT);
    kFused<<<P, 512, 0, stream>>>(x, WpT, bp, part, cpart, N, nTiles, P);
    kR<<<dim3(CDIM, 8), 512, 0, stream>>>(part, cpart, colsum, Mp, P, pch);
    kC<<<CDIM, 512, 0, stream>>>(Mp, colsum, We, be, Wo, bo, out);
}

// Round 7
// 240.785 us; speedup vs baseline: 1.1779x; 1.1779x over previous
//
#include <hip/hip_runtime.h>
#include <hip/hip_bf16.h>

typedef __attribute__((ext_vector_type(8))) short short8;
typedef __attribute__((ext_vector_type(4))) float floatx4;
typedef __attribute__((ext_vector_type(4))) unsigned uint4v;

#define FDIM 512
#define CDIM 64
#define ODIM 256
#define TR   32      // rows per tile
#define XSF  516     // xs row stride in floats (512 + 4)
#define STS 40       // sT row stride (ushort)
#define MAXP 512
// row-dependent float offset (16B units) breaking cross-quad bank aliasing;
// wave-uniform per staging instruction so global_load_lds stays legal.
#define RSW(r) ((((r) >> 3) & 3) << 2)

// round-to-nearest-even fp32 -> bf16
__device__ __forceinline__ ushort f2bf(float f) {
    union { float f; unsigned u; } v; v.f = f;
    unsigned r = v.u + 0x7FFFu + ((v.u >> 16) & 1u);
    return (ushort)(r >> 16);
}
__device__ __forceinline__ float bf2f(unsigned hi16) {
    union { unsigned u; float f; } v; v.u = hi16 << 16; return v.f;
}

// async 16B/lane global -> LDS (lds dest = wave-uniform base + lane*16)
__device__ __forceinline__ void gld16(const float* g, float* lds_base) {
    __builtin_amdgcn_global_load_lds(
        (const __attribute__((address_space(1))) unsigned int*)(const void*)g,
        (__attribute__((address_space(3))) unsigned int*)(void*)lds_base,
        16, 0, 0);
}

// ---------------- WpT[c][f] = bf16(Wp[f][c]) (64 KB, L2/L3-resident) -------
__global__ __launch_bounds__(256) void kWpT(const float* __restrict__ Wp,
                                            ushort* __restrict__ WpT) {
    int g = blockIdx.x * 256 + threadIdx.x;   // 0..32767
    int f = g >> 6, c = g & 63;
    WpT[c * FDIM + f] = f2bf(Wp[f * CDIM + c]);
}

// ---------------- Fused: per 32-row tile, s=softmax(xWp+bp); M_p += s^T x --
// Grid = P blocks; block b handles tiles b, b+P, ... 512 threads = 8 waves.
// x staged fp32 via async global_load_lds; bf16 cvt at frag-build time.
// Per-block output: bf16 partial M [64c][512f] + fp32 colsum partial [64c].
__global__ __launch_bounds__(512, 2) void kFused(
        const float* __restrict__ x, const ushort* __restrict__ WpT,
        const float* __restrict__ bp, ushort* __restrict__ part,
        float* __restrict__ cpart, int N, int nTiles, int P) {
    __shared__ float  xsf[TR * XSF + 16];  // 64.6 KB fp32 x tile (swizzled rows)
    __shared__ ushort sT[CDIM][STS];       //  5.0 KB s^T [c][row]
    __shared__ float  red1[TR][4];
    __shared__ float  red2[TR][4];
    __shared__ float  cred[CDIM][2];

    const int t    = threadIdx.x;
    const int w    = t >> 6;        // 0..7
    const int lane = t & 63;
    const int l16  = lane & 15;
    const int q    = lane >> 4;
    const int ci   = w & 3;         // phase-1 c-tile (16 c)
    const int rg   = w >> 2;        // phase-1 row half (rows 16rg..16rg+15)

    // persistent M slice: c 0..63 (mt), f in [64w,64w+64) (nt) -> 64 VGPRs
    floatx4 acc[4][4];
#pragma unroll
    for (int mt = 0; mt < 4; ++mt)
#pragma unroll
        for (int nt = 0; nt < 4; ++nt) acc[mt][nt] = (floatx4){0.f, 0.f, 0.f, 0.f};
    float csp[4] = {0.f, 0.f, 0.f, 0.f};

    float bpv[4];
#pragma unroll
    for (int reg = 0; reg < 4; ++reg) bpv[reg] = bp[16 * ci + 4 * q + reg];

    const ushort* wb = WpT + (size_t)(16 * ci + l16) * FDIM + q * 8;

    for (int tile = blockIdx.x; tile < nTiles; tile += P) {
        __syncthreads();             // guard xsf vs previous iteration readers
        const int row0 = tile * TR;

        // ---- stage x tile: 32 rows x 2 KB, async, 8 chunks/wave ----
#pragma unroll
        for (int i = 0; i < 8; ++i) {
            const int c0 = w * 8 + i;          // 0..63
            const int r  = c0 >> 1;
            const int h  = c0 & 1;
            float* lb = xsf + r * XSF + RSW(r) + h * 256;  // wave-uniform
            if (row0 + r < N) {
                const float* g = x + (size_t)(row0 + r) * FDIM + h * 256 + lane * 4;
                gld16(g, lb);
            } else {
                *(floatx4*)(lb + lane * 4) = (floatx4){0.f, 0.f, 0.f, 0.f};
            }
        }
        __syncthreads();             // drains async queue (vmcnt before barrier)

        // ---- phase 1: logitsT[c=16ci..+16][rows 16rg..+16], K=512 ----
        floatx4 acc1 = (floatx4){0.f, 0.f, 0.f, 0.f};
        const int prow = 16 * rg + l16;
        const float* xr = xsf + prow * XSF + RSW(prow);  // this lane's B row
#pragma unroll
        for (int kb = 0; kb < 4; ++kb) {
            short8 af[4];
#pragma unroll
            for (int ki = 0; ki < 4; ++ki)
                af[ki] = *(const short8*)(wb + kb * 128 + ki * 32);
#pragma unroll
            for (int ki = 0; ki < 4; ++ki) {
                const int off = kb * 128 + ki * 32 + q * 8;
                floatx4 u0 = *(const floatx4*)(xr + off);
                floatx4 u1 = *(const floatx4*)(xr + off + 4);
                short8 b;
                b[0] = (short)f2bf(u0[0]); b[1] = (short)f2bf(u0[1]);
                b[2] = (short)f2bf(u0[2]); b[3] = (short)f2bf(u0[3]);
                b[4] = (short)f2bf(u1[0]); b[5] = (short)f2bf(u1[1]);
                b[6] = (short)f2bf(u1[2]); b[7] = (short)f2bf(u1[3]);
                acc1 = __builtin_amdgcn_mfma_f32_16x16x32_bf16(af[ki], b, acc1, 0, 0, 0);
            }
        }

        // ---- softmax over c per row; lane: c=16ci+4q+reg, row=16rg+l16 ----
        const int row = prow;
        float lg[4];
#pragma unroll
        for (int reg = 0; reg < 4; ++reg) lg[reg] = acc1[reg] + bpv[reg];
        float m = fmaxf(fmaxf(lg[0], lg[1]), fmaxf(lg[2], lg[3]));
        m = fmaxf(m, __shfl_xor(m, 16));
        m = fmaxf(m, __shfl_xor(m, 32));
        if (lane < 16) red1[16 * rg + lane][ci] = m;
        __syncthreads();
        const float rmax = fmaxf(fmaxf(red1[row][0], red1[row][1]),
                                 fmaxf(red1[row][2], red1[row][3]));
        float p = 0.f;
#pragma unroll
        for (int reg = 0; reg < 4; ++reg) {
            float e = __expf(lg[reg] - rmax);
            lg[reg] = e; p += e;
        }
        p += __shfl_xor(p, 16);
        p += __shfl_xor(p, 32);
        if (lane < 16) red2[16 * rg + lane][ci] = p;
        __syncthreads();
        const float rsi = 1.0f / (red2[row][0] + red2[row][1] +
                                  red2[row][2] + red2[row][3]);
        const bool valid = (row0 + row) < N;
#pragma unroll
        for (int reg = 0; reg < 4; ++reg) {
            float s = valid ? lg[reg] * rsi : 0.f;
            sT[16 * ci + 4 * q + reg][row] = f2bf(s);
            csp[reg] += s;
        }
        __syncthreads();   // sT ready; xsf still intact

        // ---- phase 2: acc += s^T x over this tile (K=32 rows) ----
        short8 as_[4];
#pragma unroll
        for (int mt = 0; mt < 4; ++mt)
            as_[mt] = *(const short8*)&sT[16 * mt + l16][q * 8];
#pragma unroll
        for (int nt = 0; nt < 4; ++nt) {
            const int f = 64 * w + 16 * nt + l16;
            short8 b;
#pragma unroll
            for (int j = 0; j < 8; ++j)      // row 8q+j -> RSW = 4q
                b[j] = (short)f2bf(xsf[(q * 8 + j) * XSF + 4 * q + f]);
#pragma unroll
            for (int mt = 0; mt < 4; ++mt)
                acc[mt][nt] = __builtin_amdgcn_mfma_f32_16x16x32_bf16(
                    as_[mt], b, acc[mt][nt], 0, 0, 0);
        }
    }

    // ---- per-block colsum partial (fp32, no atomics) ----
#pragma unroll
    for (int reg = 0; reg < 4; ++reg) {
        float v = csp[reg];
        v += __shfl_xor(v, 1); v += __shfl_xor(v, 2);
        v += __shfl_xor(v, 4); v += __shfl_xor(v, 8);
        if (l16 == 0) cred[16 * ci + 4 * q + reg][rg] = v;
    }
    __syncthreads();   // all waves done with xsf (phase-2 complete)
    if (t < 64) cpart[(size_t)blockIdx.x * CDIM + t] = cred[t][0] + cred[t][1];

    // ---- flush: acc -> xsf scratch (bf16) -> coalesced uint4 store ----
    ushort* xf = (ushort*)xsf;
#pragma unroll
    for (int mt = 0; mt < 4; ++mt)
#pragma unroll
        for (int nt = 0; nt < 4; ++nt)
#pragma unroll
            for (int reg = 0; reg < 4; ++reg)
                xf[(16 * mt + 4 * q + reg) * FDIM + 64 * w + 16 * nt + l16] =
                    f2bf(acc[mt][nt][reg]);
    __syncthreads();
    const uint4v* src = (const uint4v*)xf;
    uint4v* dst = (uint4v*)(part + (size_t)blockIdx.x * (CDIM * FDIM));
#pragma unroll
    for (int i = 0; i < 8; ++i)
        dst[i * 512 + t] = src[i * 512 + t];
}

// ---------------- stage-1 reduce: P partials -> 8 fp32 slices + colsum -----
// grid (64 c, 8 p-chunks), 512 threads (t = f).
__global__ __launch_bounds__(512) void kR(const ushort* __restrict__ part,
                                          const float* __restrict__ cpart,
                                          float* __restrict__ colsum,
                                          float* __restrict__ Mp,
                                          int P, int pch) {
    __shared__ float ws8[8];
    const int c = blockIdx.x, pc = blockIdx.y, t = threadIdx.x;
    const int p0 = pc * pch, p1 = min(p0 + pch, P);

    float sum = 0.f;
    const ushort* pp = part + (size_t)c * FDIM + t;
#pragma unroll 4
    for (int p = p0; p < p1; ++p)
        sum += bf2f((unsigned)pp[(size_t)p * (CDIM * FDIM)]);
    Mp[((size_t)pc * CDIM + c) * FDIM + t] = sum;

    // colsum chunk (p = p0 + t)
    float cv = 0.f;
    {
        int p = p0 + t;
        if (p < p1) cv = cpart[(size_t)p * CDIM + c];
    }
    cv += __shfl_xor(cv, 1);  cv += __shfl_xor(cv, 2);
    cv += __shfl_xor(cv, 4);  cv += __shfl_xor(cv, 8);
    cv += __shfl_xor(cv, 16); cv += __shfl_xor(cv, 32);
    if ((t & 63) == 0) ws8[t >> 6] = cv;
    __syncthreads();
    if (t == 0) {
        float tot = 0.f;
#pragma unroll
        for (int i = 0; i < 8; ++i) tot += ws8[i];
        atomicAdd(colsum + c, tot);     // 512 adds total, uncontended
    }
}

// ---------------- epilogue: Mp -> M -> pooled -> out -----------------------
__global__ __launch_bounds__(512) void kC(const float* __restrict__ Mp,
                                          const float* __restrict__ colsum,
                                          const float* __restrict__ We,
                                          const float* __restrict__ be,
                                          const float* __restrict__ Wo,
                                          const float* __restrict__ bo,
                                          float* __restrict__ out) {
    __shared__ float Mrow[512];
    __shared__ float pooled[512];
    __shared__ float halves[2][256];
    const int c = blockIdx.x, t = threadIdx.x;

    float sum = 0.f;
#pragma unroll
    for (int pc = 0; pc < 8; ++pc)
        sum += Mp[((size_t)pc * CDIM + c) * FDIM + t];
    Mrow[t] = sum;
    __syncthreads();

    float a = colsum[c] * be[t];
#pragma unroll 16
    for (int k = 0; k < FDIM; ++k)
        a = fmaf(Mrow[k], We[(size_t)k * FDIM + t], a);
    pooled[t] = a;
    __syncthreads();

    const int o = t & 255, h = t >> 8;
    float b = 0.f;
#pragma unroll 16
    for (int kk = 0; kk < 256; ++kk) {
        int k = h * 256 + kk;
        b = fmaf(pooled[k], Wo[(size_t)k * ODIM + o], b);
    }
    halves[h][o] = b;
    __syncthreads();
    if (t < 256)
        out[(size_t)c * ODIM + t] = halves[0][t] + halves[1][t] + bo[t];
}

// ---------------------------------------------------------------------------
extern "C" void kernel_launch(void* const* d_in, const int* in_sizes, int n_in,
                              void* d_out, int out_size, void* d_ws, size_t ws_size,
                              hipStream_t stream) {
    const float* x  = (const float*)d_in[0];
    // d_in[1] edge_index, d_in[2] batch: unused by reference output
    const float* Wp = (const float*)d_in[3];
    const float* bp = (const float*)d_in[4];
    const float* We = (const float*)d_in[5];
    const float* be = (const float*)d_in[6];
    const float* Wo = (const float*)d_in[7];
    const float* bo = (const float*)d_in[8];
    float* out = (float*)d_out;

    const int N = in_sizes[0] / FDIM;          // 50000
    const int nTiles = (N + TR - 1) / TR;      // 1563

    // ws bytes:
    //   [0,       65536)  WpT bf16
    //   [65536,   65792)  colsum fp32
    //   [66560,  266752)  cpart fp32
    //   [266752,1315328)  Mp fp32 (8 x 64 x 512)
    //   [1315328, ...)    part bf16 (P x 64 KB)
    char*   wsb    = (char*)d_ws;
    ushort* WpT    = (ushort*)wsb;
    float*  colsum = (float*)(wsb + 65536);
    float*  cpart  = (float*)(wsb + 66560);
    float*  Mp     = (float*)(wsb + 266752);
    const size_t PART_OFF = 1315328;
    ushort* part   = (ushort*)(wsb + PART_OFF);

    size_t avail = (ws_size > PART_OFF + 65536) ? (ws_size - PART_OFF) / 65536 : 1;
    int P = (int)(avail < (size_t)MAXP ? avail : (size_t)MAXP);
    if (P > nTiles) P = nTiles;
    if (P < 1) P = 1;
    const int pch = (P + 7) / 8;

    hipMemsetAsync(colsum, 0, 256, stream);
    kWpT<<<128, 256, 0, stream>>>(Wp, WpT);
    kFused<<<P, 512, 0, stream>>>(x, WpT, bp, part, cpart, N, nTiles, P);
    kR<<<dim3(CDIM, 8), 512, 0, stream>>>(part, cpart, colsum, Mp, P, pch);
    kC<<<CDIM, 512, 0, stream>>>(Mp, colsum, We, be, Wo, bo, out);
}